// Round 1
// baseline (1962.988 us; speedup 1.0000x reference)
//
#include <hip/hip_runtime.h>
#include <math.h>

#define Bsz 4
#define Tseq 2048
#define Ed 1024
#define Hh 16
#define Dh 64
#define E3 (3*Ed)

// ---------------- fp32 tiled GEMM: C[M,N] = A[M,K]*B[K,N] (row-major) -------
// BM=BN=128, BK=16, 256 threads, 8x8 micro-tile per thread.
template<int M, int N, int KD>
__global__ __launch_bounds__(256)
void gemm_f32(const float* __restrict__ A, const float* __restrict__ Bm,
              float* __restrict__ C) {
  constexpr int BM = 128, BN = 128, BK = 16;
  __shared__ float As[BK][BM + 4];   // [k][m] transposed, +4 pad
  __shared__ float Bs[BK][BN + 4];   // [k][n]
  const int tid = threadIdx.x;
  const int tx = tid & 15, ty = tid >> 4;
  const int m0 = blockIdx.y * BM, n0 = blockIdx.x * BN;

  float acc[8][8];
  #pragma unroll
  for (int i = 0; i < 8; ++i)
    #pragma unroll
    for (int j = 0; j < 8; ++j) acc[i][j] = 0.f;

  for (int kt = 0; kt < KD; kt += BK) {
    // stage A tile (128 rows x 16 k), transposed into LDS
    #pragma unroll
    for (int i = 0; i < 2; ++i) {
      int f = tid + i * 256;                 // 512 float4 units
      int row = f >> 2, kq = f & 3;
      float4 a = *(const float4*)(A + (size_t)(m0 + row) * KD + kt + kq * 4);
      As[kq*4+0][row] = a.x; As[kq*4+1][row] = a.y;
      As[kq*4+2][row] = a.z; As[kq*4+3][row] = a.w;
    }
    // stage B tile (16 k x 128 cols), natural layout
    #pragma unroll
    for (int i = 0; i < 2; ++i) {
      int f = tid + i * 256;
      int kr = f >> 5, nq = f & 31;
      *(float4*)&Bs[kr][nq*4] =
          *(const float4*)(Bm + (size_t)(kt + kr) * N + n0 + nq * 4);
    }
    __syncthreads();
    #pragma unroll
    for (int k = 0; k < BK; ++k) {
      float a[8], b[8];
      *(float4*)&a[0] = *(const float4*)&As[k][ty * 8];
      *(float4*)&a[4] = *(const float4*)&As[k][ty * 8 + 4];
      *(float4*)&b[0] = *(const float4*)&Bs[k][tx * 8];
      *(float4*)&b[4] = *(const float4*)&Bs[k][tx * 8 + 4];
      #pragma unroll
      for (int i = 0; i < 8; ++i)
        #pragma unroll
        for (int j = 0; j < 8; ++j) acc[i][j] = fmaf(a[i], b[j], acc[i][j]);
    }
    __syncthreads();
  }
  #pragma unroll
  for (int i = 0; i < 8; ++i) {
    float* cp = C + (size_t)(m0 + ty * 8 + i) * N + n0 + tx * 8;
    float4 c0 = make_float4(acc[i][0], acc[i][1], acc[i][2], acc[i][3]);
    float4 c1 = make_float4(acc[i][4], acc[i][5], acc[i][6], acc[i][7]);
    *(float4*)cp = c0;
    *(float4*)(cp + 4) = c1;
  }
}

// ---------------- causal flash attention, fp32 ------------------------------
// grid (T/64, B*H); block 256 = 16x16 threads, 4x4 micro-tile.
// LDS exactly 64 KiB: Qs/Ks transposed [d][token] with XOR swizzle on the
// float4-column index (kills 16-way scalar-write conflicts without padding).
__global__ __launch_bounds__(256)
void flash_causal(const float* __restrict__ qkv, float* __restrict__ y) {
  __shared__ float Qs[64][64];   // [d][r] swizzled
  __shared__ float Ks[64][64];   // [d][c] swizzled
  __shared__ float Vs[64][64];   // [c][d] natural
  __shared__ float Ps[64][64];   // [r][c] natural
  const int qt = blockIdx.x, bh = blockIdx.y;
  const int b = bh >> 4, h = bh & 15;
  const int tid = threadIdx.x;
  const int tx = tid & 15, ty = tid >> 4;
  const size_t rowbase = (size_t)b * Tseq;
  const int qoff = h * 64;

  // load Q tile transposed+swizzled: element (d=dg*4+j, r) -> col ((r>>2)^(dg&7))*4 + (r&3)
  #pragma unroll
  for (int i = 0; i < 4; ++i) {
    int f = tid + i * 256;
    int r = f >> 4, dg = f & 15;
    float4 q4 = *(const float4*)(qkv + (rowbase + qt*64 + r) * E3 + qoff + dg*4);
    int col = ((((r >> 2) ^ (dg & 7)) << 2) | (r & 3));
    Qs[dg*4+0][col] = q4.x; Qs[dg*4+1][col] = q4.y;
    Qs[dg*4+2][col] = q4.z; Qs[dg*4+3][col] = q4.w;
  }

  float m_i[4], l_i[4], o[4][4];
  #pragma unroll
  for (int i = 0; i < 4; ++i) {
    m_i[i] = -3.0e38f; l_i[i] = 0.f;
    #pragma unroll
    for (int j = 0; j < 4; ++j) o[i][j] = 0.f;
  }

  for (int kt = 0; kt <= qt; ++kt) {
    // stage K (transposed+swizzled) and V (natural)
    #pragma unroll
    for (int i = 0; i < 4; ++i) {
      int f = tid + i * 256;
      int c = f >> 4, dg = f & 15;
      const float* kvp = qkv + (rowbase + kt*64 + c) * E3 + qoff;
      float4 k4 = *(const float4*)(kvp + Ed + dg*4);
      int col = ((((c >> 2) ^ (dg & 7)) << 2) | (c & 3));
      Ks[dg*4+0][col] = k4.x; Ks[dg*4+1][col] = k4.y;
      Ks[dg*4+2][col] = k4.z; Ks[dg*4+3][col] = k4.w;
      float4 v4 = *(const float4*)(kvp + 2*Ed + dg*4);
      *(float4*)&Vs[c][dg*4] = v4;
    }
    __syncthreads();

    // S = Q K^T  (rows 4ty.., cols 4tx..)
    float s[4][4];
    #pragma unroll
    for (int i = 0; i < 4; ++i)
      #pragma unroll
      for (int j = 0; j < 4; ++j) s[i][j] = 0.f;
    for (int d0 = 0; d0 < 64; d0 += 4) {
      int sw = (d0 >> 2) & 7;
      #pragma unroll
      for (int dd = 0; dd < 4; ++dd) {
        float qa[4], kb[4];
        *(float4*)qa = *(const float4*)&Qs[d0+dd][(ty ^ sw) << 2];
        *(float4*)kb = *(const float4*)&Ks[d0+dd][(tx ^ sw) << 2];
        #pragma unroll
        for (int i = 0; i < 4; ++i)
          #pragma unroll
          for (int j = 0; j < 4; ++j) s[i][j] = fmaf(qa[i], kb[j], s[i][j]);
      }
    }
    #pragma unroll
    for (int i = 0; i < 4; ++i)
      #pragma unroll
      for (int j = 0; j < 4; ++j) s[i][j] *= 0.125f;   // 1/sqrt(64)
    if (kt == qt) {
      #pragma unroll
      for (int i = 0; i < 4; ++i)
        #pragma unroll
        for (int j = 0; j < 4; ++j)
          if (tx*4 + j > ty*4 + i) s[i][j] = -3.0e38f;
    }

    // online softmax per row (reduce across the 16 tx lanes of this wave)
    #pragma unroll
    for (int i = 0; i < 4; ++i) {
      float mx = fmaxf(fmaxf(s[i][0], s[i][1]), fmaxf(s[i][2], s[i][3]));
      mx = fmaxf(mx, __shfl_xor(mx, 1, 16));
      mx = fmaxf(mx, __shfl_xor(mx, 2, 16));
      mx = fmaxf(mx, __shfl_xor(mx, 4, 16));
      mx = fmaxf(mx, __shfl_xor(mx, 8, 16));
      float mnew = fmaxf(m_i[i], mx);
      float alpha = __expf(m_i[i] - mnew);
      float p0 = __expf(s[i][0] - mnew);
      float p1 = __expf(s[i][1] - mnew);
      float p2 = __expf(s[i][2] - mnew);
      float p3 = __expf(s[i][3] - mnew);
      float rs = p0 + p1 + p2 + p3;
      rs += __shfl_xor(rs, 1, 16);
      rs += __shfl_xor(rs, 2, 16);
      rs += __shfl_xor(rs, 4, 16);
      rs += __shfl_xor(rs, 8, 16);
      l_i[i] = l_i[i] * alpha + rs;
      m_i[i] = mnew;
      #pragma unroll
      for (int j = 0; j < 4; ++j) o[i][j] *= alpha;
      float4 pv = make_float4(p0, p1, p2, p3);
      *(float4*)&Ps[ty*4+i][tx*4] = pv;
    }
    __syncthreads();

    // O += P V   (O rows 4ty.., d-cols 4tx..)
    for (int c0 = 0; c0 < 64; c0 += 4) {
      float pr[4][4], vr[4][4];
      #pragma unroll
      for (int i = 0; i < 4; ++i)
        *(float4*)pr[i] = *(const float4*)&Ps[ty*4+i][c0];
      #pragma unroll
      for (int cc = 0; cc < 4; ++cc)
        *(float4*)vr[cc] = *(const float4*)&Vs[c0+cc][tx*4];
      #pragma unroll
      for (int i = 0; i < 4; ++i)
        #pragma unroll
        for (int cc = 0; cc < 4; ++cc)
          #pragma unroll
          for (int j = 0; j < 4; ++j)
            o[i][j] = fmaf(pr[i][cc], vr[cc][j], o[i][j]);
    }
    __syncthreads();
  }

  // epilogue: y[b, t, h*64 + d] (y layout [B,T,E])
  #pragma unroll
  for (int i = 0; i < 4; ++i) {
    float inv = 1.f / l_i[i];
    float4 ov = make_float4(o[i][0]*inv, o[i][1]*inv, o[i][2]*inv, o[i][3]*inv);
    *(float4*)(y + (rowbase + qt*64 + ty*4 + i) * Ed + qoff + tx*4) = ov;
  }
}

// ---------------- mem attention (K=3, scale 4096) + gated fusion ------------
// one wave per (b,t,h); lane = d. Overwrites y in place with `combined`.
__global__ __launch_bounds__(256)
void mem_gate(const float* __restrict__ qkv, const float* __restrict__ mem_k,
              const float* __restrict__ mem_v, const float* __restrict__ gate,
              float* __restrict__ y) {
  const int tid = threadIdx.x;
  const int lane = tid & 63;
  const int g = (blockIdx.x << 2) | (tid >> 6);  // wave id over B*T*H
  const int h = g & 15;
  const int bt = g >> 4;
  const float q = qkv[(size_t)bt * E3 + h*64 + lane];
  const size_t mb = ((size_t)bt * 3) * Ed + h*64 + lane;

  float s[3];
  #pragma unroll
  for (int k = 0; k < 3; ++k) {
    float p = q * mem_k[mb + (size_t)k * Ed];
    p += __shfl_xor(p, 1);  p += __shfl_xor(p, 2);  p += __shfl_xor(p, 4);
    p += __shfl_xor(p, 8);  p += __shfl_xor(p, 16); p += __shfl_xor(p, 32);
    s[k] = p * 4096.0f;   // mem_scale = E * sqrt(H)
  }
  float mx = fmaxf(s[0], fmaxf(s[1], s[2]));
  float w0 = __expf(s[0] - mx), w1 = __expf(s[1] - mx), w2 = __expf(s[2] - mx);
  float inv = 1.f / (w0 + w1 + w2);
  float ov = (w0 * mem_v[mb] + w1 * mem_v[mb + Ed] + w2 * mem_v[mb + 2*Ed]) * inv;
  float gb = gate[h];
  float* yp = y + (size_t)bt * Ed + h*64 + lane;
  *yp = ov * gb + (*yp) * (1.f - gb);
}

extern "C" void kernel_launch(void* const* d_in, const int* in_sizes, int n_in,
                              void* d_out, int out_size, void* d_ws, size_t ws_size,
                              hipStream_t stream) {
  const float* x      = (const float*)d_in[0];
  const float* mem_k  = (const float*)d_in[1];
  const float* mem_v  = (const float*)d_in[2];
  const float* W_attn = (const float*)d_in[3];
  const float* W_proj = (const float*)d_in[4];
  const float* gate   = (const float*)d_in[5];
  float* out = (float*)d_out;

  float* qkv = (float*)d_ws;                         // [B*T, 3E]  100.7 MB
  float* y   = qkv + (size_t)Bsz * Tseq * E3;        // [B*T, E]   33.6 MB (y -> combined in place)

  // 1) qkv = x @ W_attn  (fp32 — mem-attn softmax scale 4096 needs fp32 q)
  gemm_f32<Bsz*Tseq, E3, Ed>
      <<<dim3(E3/128, (Bsz*Tseq)/128), 256, 0, stream>>>(x, W_attn, qkv);
  // 2) y = causal SDPA(q,k,v)
  flash_causal<<<dim3(Tseq/64, Bsz*Hh), 256, 0, stream>>>(qkv, y);
  // 3) y = gate*memattn + (1-gate)*y   (in place)
  mem_gate<<<(Bsz*Tseq*Hh)/4, 256, 0, stream>>>(qkv, mem_k, mem_v, gate, y);
  // 4) out = y @ W_proj
  gemm_f32<Bsz*Tseq, Ed, Ed>
      <<<dim3(Ed/128, (Bsz*Tseq)/128), 256, 0, stream>>>(y, W_proj, out);
}

// Round 2
// 1271.538 us; speedup vs baseline: 1.5438x; 1.5438x over previous
//
#include <hip/hip_runtime.h>
#include <math.h>

#define Bsz 4
#define Tseq 2048
#define Ed 1024
#define Hh 16
#define E3 (3*Ed)

typedef short short8 __attribute__((ext_vector_type(8)));
typedef float floatx4 __attribute__((ext_vector_type(4)));

__device__ __forceinline__ unsigned short f2bf(float f) {
  unsigned int u = __builtin_bit_cast(unsigned int, f);
  u += 0x7fffu + ((u >> 16) & 1u);           // RNE (finite inputs)
  return (unsigned short)(u >> 16);
}

// swizzled element index in a 64-col bf16 tile (group-of-8 XOR on row)
__device__ __forceinline__ int swz(int row, int col) {
  return row * 64 + ((((col >> 3) ^ (row & 7)) << 3) | (col & 7));
}

// ---------------- fp32 tiled GEMM: C[M,N] = A[M,K]*B[K,N] (row-major) -------
template<int M, int N, int KD>
__global__ __launch_bounds__(256)
void gemm_f32(const float* __restrict__ A, const float* __restrict__ Bm,
              float* __restrict__ C) {
  constexpr int BM = 128, BN = 128, BK = 16;
  __shared__ float As[BK][BM + 4];
  __shared__ float Bs[BK][BN + 4];
  const int tid = threadIdx.x;
  const int tx = tid & 15, ty = tid >> 4;
  const int m0 = blockIdx.y * BM, n0 = blockIdx.x * BN;

  float acc[8][8];
  #pragma unroll
  for (int i = 0; i < 8; ++i)
    #pragma unroll
    for (int j = 0; j < 8; ++j) acc[i][j] = 0.f;

  for (int kt = 0; kt < KD; kt += BK) {
    #pragma unroll
    for (int i = 0; i < 2; ++i) {
      int f = tid + i * 256;
      int row = f >> 2, kq = f & 3;
      float4 a = *(const float4*)(A + (size_t)(m0 + row) * KD + kt + kq * 4);
      As[kq*4+0][row] = a.x; As[kq*4+1][row] = a.y;
      As[kq*4+2][row] = a.z; As[kq*4+3][row] = a.w;
    }
    #pragma unroll
    for (int i = 0; i < 2; ++i) {
      int f = tid + i * 256;
      int kr = f >> 5, nq = f & 31;
      *(float4*)&Bs[kr][nq*4] =
          *(const float4*)(Bm + (size_t)(kt + kr) * N + n0 + nq * 4);
    }
    __syncthreads();
    #pragma unroll
    for (int k = 0; k < BK; ++k) {
      float a[8], b[8];
      *(float4*)&a[0] = *(const float4*)&As[k][ty * 8];
      *(float4*)&a[4] = *(const float4*)&As[k][ty * 8 + 4];
      *(float4*)&b[0] = *(const float4*)&Bs[k][tx * 8];
      *(float4*)&b[4] = *(const float4*)&Bs[k][tx * 8 + 4];
      #pragma unroll
      for (int i = 0; i < 8; ++i)
        #pragma unroll
        for (int j = 0; j < 8; ++j) acc[i][j] = fmaf(a[i], b[j], acc[i][j]);
    }
    __syncthreads();
  }
  #pragma unroll
  for (int i = 0; i < 8; ++i) {
    float* cp = C + (size_t)(m0 + ty * 8 + i) * N + n0 + tx * 8;
    *(float4*)cp = make_float4(acc[i][0], acc[i][1], acc[i][2], acc[i][3]);
    *(float4*)(cp + 4) = make_float4(acc[i][4], acc[i][5], acc[i][6], acc[i][7]);
  }
}

// ---------------- causal flash attention, bf16 MFMA -------------------------
// grid (T/128, B*H); block 256 = 4 waves; each wave owns 32 q-rows.
// Q A-frags direct from global (once). K natural / V transposed in swizzled
// bf16 LDS tiles. P round-trips through per-wave LDS (C-layout -> A-layout).
__global__ __launch_bounds__(256)
void flash_mfma(const float* __restrict__ qkv, float* __restrict__ y) {
  __shared__ __align__(16) unsigned short Ks[64 * 64];      // [key][d] swizzled
  __shared__ __align__(16) unsigned short Vt[64 * 64];      // [d][key] swizzled
  __shared__ __align__(16) unsigned short Ps[4][32 * 64];   // per-wave [qrow][key]
  const int q = blockIdx.x;             // 128-row q tile
  const int bh = blockIdx.y;
  const int b = bh >> 4, h = bh & 15;
  const int tid = threadIdx.x;
  const int w = tid >> 6, L = tid & 63;
  const int Ln = L & 15, Lq = L >> 4;
  const size_t base = (size_t)b * Tseq;
  const int q0 = q * 128;
  const int hof = h * 64;

  // Q A-fragments, fp32 global -> bf16 regs. qf[mt][kc]
  short8 qf[2][2];
  #pragma unroll
  for (int mt = 0; mt < 2; ++mt) {
    const float* qp = qkv + (base + q0 + w*32 + mt*16 + Ln) * E3 + hof;
    #pragma unroll
    for (int kc = 0; kc < 2; ++kc) {
      float v[8];
      *(float4*)&v[0] = *(const float4*)(qp + kc*32 + Lq*8);
      *(float4*)&v[4] = *(const float4*)(qp + kc*32 + Lq*8 + 4);
      short8 t;
      #pragma unroll
      for (int j = 0; j < 8; ++j) t[j] = (short)f2bf(v[j]);
      qf[mt][kc] = t;
    }
  }

  float m_i[2][4], l_i[2][4];
  floatx4 O[2][4];
  #pragma unroll
  for (int mt = 0; mt < 2; ++mt)
    #pragma unroll
    for (int r = 0; r < 4; ++r) { m_i[mt][r] = -3.0e38f; l_i[mt][r] = 0.f; }
  #pragma unroll
  for (int mt = 0; mt < 2; ++mt)
    #pragma unroll
    for (int nt = 0; nt < 4; ++nt) O[mt][nt] = (floatx4)0.f;

  const int nkt = 2 * q + 2;
  for (int kt = 0; kt < nkt; ++kt) {
    // ---- stage K (natural) and V (transposed), fp32 -> bf16, swizzled ----
    #pragma unroll
    for (int i = 0; i < 4; ++i) {
      int f = tid + i * 256;
      int c = f >> 4, dg = f & 15;
      const float* kvp = qkv + (base + kt*64 + c) * E3 + hof + dg*4;
      float4 k4 = *(const float4*)(kvp + Ed);
      float4 v4 = *(const float4*)(kvp + 2*Ed);
      unsigned int k01 = (unsigned)f2bf(k4.x) | ((unsigned)f2bf(k4.y) << 16);
      unsigned int k23 = (unsigned)f2bf(k4.z) | ((unsigned)f2bf(k4.w) << 16);
      int ka = c*64 + ((((dg>>1) ^ (c & 7)) << 3) | ((dg & 1) * 4));
      *(uint2*)&Ks[ka] = make_uint2(k01, k23);
      float vv[4] = {v4.x, v4.y, v4.z, v4.w};
      #pragma unroll
      for (int j = 0; j < 4; ++j) Vt[swz(dg*4 + j, c)] = f2bf(vv[j]);
    }
    __syncthreads();

    // ---- S = Q K^T  (B-frags from Ks) ----
    short8 kb[4][2];
    #pragma unroll
    for (int nt = 0; nt < 4; ++nt) {
      int krow = nt*16 + Ln;
      #pragma unroll
      for (int kc = 0; kc < 2; ++kc)
        kb[nt][kc] = *(const short8*)&Ks[krow*64 + ((((kc*4 + Lq) ^ (krow & 7)) << 3))];
    }
    floatx4 S[2][4];
    #pragma unroll
    for (int mt = 0; mt < 2; ++mt)
      #pragma unroll
      for (int nt = 0; nt < 4; ++nt) {
        floatx4 acc = (floatx4)0.f;
        acc = __builtin_amdgcn_mfma_f32_16x16x32_bf16(qf[mt][0], kb[nt][0], acc, 0, 0, 0);
        acc = __builtin_amdgcn_mfma_f32_16x16x32_bf16(qf[mt][1], kb[nt][1], acc, 0, 0, 0);
        S[mt][nt] = acc;
      }

    // scale + causal mask (only the last two kt tiles can touch the diagonal)
    #pragma unroll
    for (int mt = 0; mt < 2; ++mt)
      #pragma unroll
      for (int nt = 0; nt < 4; ++nt)
        #pragma unroll
        for (int r = 0; r < 4; ++r) S[mt][nt][r] *= 0.125f;
    if (kt >= 2*q) {
      #pragma unroll
      for (int mt = 0; mt < 2; ++mt) {
        int rowg = q0 + w*32 + mt*16 + Lq*4;
        #pragma unroll
        for (int nt = 0; nt < 4; ++nt) {
          int colg = kt*64 + nt*16 + Ln;
          #pragma unroll
          for (int r = 0; r < 4; ++r)
            if (colg > rowg + r) S[mt][nt][r] = -3.0e38f;
        }
      }
    }

    // ---- online softmax (rows live across the 16 lanes sharing Lq) ----
    #pragma unroll
    for (int mt = 0; mt < 2; ++mt) {
      #pragma unroll
      for (int r = 0; r < 4; ++r) {
        float mx = fmaxf(fmaxf(S[mt][0][r], S[mt][1][r]),
                         fmaxf(S[mt][2][r], S[mt][3][r]));
        mx = fmaxf(mx, __shfl_xor(mx, 1));
        mx = fmaxf(mx, __shfl_xor(mx, 2));
        mx = fmaxf(mx, __shfl_xor(mx, 4));
        mx = fmaxf(mx, __shfl_xor(mx, 8));
        float mnew = fmaxf(m_i[mt][r], mx);
        float alpha = __expf(m_i[mt][r] - mnew);
        m_i[mt][r] = mnew;
        float rs = 0.f;
        #pragma unroll
        for (int nt = 0; nt < 4; ++nt) {
          float p = __expf(S[mt][nt][r] - mnew);
          S[mt][nt][r] = p;
          rs += p;
        }
        rs += __shfl_xor(rs, 1);
        rs += __shfl_xor(rs, 2);
        rs += __shfl_xor(rs, 4);
        rs += __shfl_xor(rs, 8);
        l_i[mt][r] = l_i[mt][r] * alpha + rs;
        #pragma unroll
        for (int nt = 0; nt < 4; ++nt) O[mt][nt][r] *= alpha;
        // P -> per-wave LDS (C-layout scatter, swizzled)
        int prow = mt*16 + Lq*4 + r;
        #pragma unroll
        for (int nt = 0; nt < 4; ++nt)
          Ps[w][swz(prow, nt*16 + Ln)] = f2bf(S[mt][nt][r]);
      }
    }

    // ---- O += P V  (A-frags from Ps, B-frags from Vt) ----
    short8 vb[4][2], pf[2][2];
    #pragma unroll
    for (int nt = 0; nt < 4; ++nt) {
      int vrow = nt*16 + Ln;
      #pragma unroll
      for (int kc = 0; kc < 2; ++kc)
        vb[nt][kc] = *(const short8*)&Vt[vrow*64 + ((((kc*4 + Lq) ^ (vrow & 7)) << 3))];
    }
    #pragma unroll
    for (int mt = 0; mt < 2; ++mt) {
      int prow = mt*16 + Ln;
      #pragma unroll
      for (int kc = 0; kc < 2; ++kc)
        pf[mt][kc] = *(const short8*)&Ps[w][prow*64 + ((((kc*4 + Lq) ^ (prow & 7)) << 3))];
    }
    #pragma unroll
    for (int mt = 0; mt < 2; ++mt)
      #pragma unroll
      for (int nt = 0; nt < 4; ++nt) {
        O[mt][nt] = __builtin_amdgcn_mfma_f32_16x16x32_bf16(pf[mt][0], vb[nt][0], O[mt][nt], 0, 0, 0);
        O[mt][nt] = __builtin_amdgcn_mfma_f32_16x16x32_bf16(pf[mt][1], vb[nt][1], O[mt][nt], 0, 0, 0);
      }
    __syncthreads();
  }

  // epilogue: y[b, row, h*64 + d], C-layout scatter (16-lane rows coalesce 64B)
  #pragma unroll
  for (int mt = 0; mt < 2; ++mt) {
    #pragma unroll
    for (int r = 0; r < 4; ++r) {
      float inv = 1.f / l_i[mt][r];
      size_t rb = (base + q0 + w*32 + mt*16 + Lq*4 + r) * Ed + hof;
      #pragma unroll
      for (int nt = 0; nt < 4; ++nt)
        y[rb + nt*16 + Ln] = O[mt][nt][r] * inv;
    }
  }
}

// ---------------- mem attention (K=3, scale 4096) + gated fusion ------------
__global__ __launch_bounds__(256)
void mem_gate(const float* __restrict__ qkv, const float* __restrict__ mem_k,
              const float* __restrict__ mem_v, const float* __restrict__ gate,
              float* __restrict__ y) {
  const int tid = threadIdx.x;
  const int lane = tid & 63;
  const int g = (blockIdx.x << 2) | (tid >> 6);
  const int h = g & 15;
  const int bt = g >> 4;
  const float q = qkv[(size_t)bt * E3 + h*64 + lane];
  const size_t mb = ((size_t)bt * 3) * Ed + h*64 + lane;

  float s[3];
  #pragma unroll
  for (int k = 0; k < 3; ++k) {
    float p = q * mem_k[mb + (size_t)k * Ed];
    p += __shfl_xor(p, 1);  p += __shfl_xor(p, 2);  p += __shfl_xor(p, 4);
    p += __shfl_xor(p, 8);  p += __shfl_xor(p, 16); p += __shfl_xor(p, 32);
    s[k] = p * 4096.0f;
  }
  float mx = fmaxf(s[0], fmaxf(s[1], s[2]));
  float w0 = __expf(s[0] - mx), w1 = __expf(s[1] - mx), w2 = __expf(s[2] - mx);
  float inv = 1.f / (w0 + w1 + w2);
  float ov = (w0 * mem_v[mb] + w1 * mem_v[mb + Ed] + w2 * mem_v[mb + 2*Ed]) * inv;
  float gb = gate[h];
  float* yp = y + (size_t)bt * Ed + h*64 + lane;
  *yp = ov * gb + (*yp) * (1.f - gb);
}

extern "C" void kernel_launch(void* const* d_in, const int* in_sizes, int n_in,
                              void* d_out, int out_size, void* d_ws, size_t ws_size,
                              hipStream_t stream) {
  const float* x      = (const float*)d_in[0];
  const float* mem_k  = (const float*)d_in[1];
  const float* mem_v  = (const float*)d_in[2];
  const float* W_attn = (const float*)d_in[3];
  const float* W_proj = (const float*)d_in[4];
  const float* gate   = (const float*)d_in[5];
  float* out = (float*)d_out;

  float* qkv = (float*)d_ws;                     // [B*T, 3E]
  float* y   = qkv + (size_t)Bsz * Tseq * E3;    // [B*T, E]

  gemm_f32<Bsz*Tseq, E3, Ed>
      <<<dim3(E3/128, (Bsz*Tseq)/128), 256, 0, stream>>>(x, W_attn, qkv);
  flash_mfma<<<dim3(Tseq/128, Bsz*Hh), 256, 0, stream>>>(qkv, y);
  mem_gate<<<(Bsz*Tseq*Hh)/4, 256, 0, stream>>>(qkv, mem_k, mem_v, gate, y);
  gemm_f32<Bsz*Tseq, Ed, Ed>
      <<<dim3(Ed/128, (Bsz*Tseq)/128), 256, 0, stream>>>(y, W_proj, out);
}

// Round 3
// 807.151 us; speedup vs baseline: 2.4320x; 1.5753x over previous
//
#include <hip/hip_runtime.h>
#include <math.h>

#define Bsz 4
#define Tseq 2048
#define Ed 1024
#define Hh 16
#define E3 (3*Ed)
#define MROWS (Bsz*Tseq)

typedef short short8 __attribute__((ext_vector_type(8)));
typedef float floatx4 __attribute__((ext_vector_type(4)));

__device__ __forceinline__ unsigned short f2bf(float f) {
  unsigned int u = __builtin_bit_cast(unsigned int, f);
  u += 0x7fffu + ((u >> 16) & 1u);           // RNE (finite inputs)
  return (unsigned short)(u >> 16);
}
__device__ __forceinline__ float bf2f(unsigned short u) {
  return __builtin_bit_cast(float, ((unsigned int)u) << 16);
}
// swizzled element index in a 64-col bf16 tile (group-of-8 XOR on row)
__device__ __forceinline__ int swz(int row, int col) {
  return row * 64 + ((((col >> 3) ^ (row & 7)) << 3) | (col & 7));
}

// ---------------- fp32 -> bf16 cast (x) -------------------------------------
__global__ __launch_bounds__(256)
void cast_bf16_k(const float* __restrict__ s, unsigned short* __restrict__ d, int n4) {
  int i = blockIdx.x * 256 + threadIdx.x;
  if (i >= n4) return;
  float4 v = ((const float4*)s)[i];
  unsigned short o[4] = {f2bf(v.x), f2bf(v.y), f2bf(v.z), f2bf(v.w)};
  ((uint2*)d)[i] = *(uint2*)o;
}

// ---------------- fp32 [K][ld] (col window c0) -> bf16 [N][K] transpose -----
__global__ __launch_bounds__(256)
void transpose_cast(const float* __restrict__ src, int ld, int c0,
                    unsigned short* __restrict__ dst, int Krows) {
  __shared__ float t[64][65];
  const int kb = blockIdx.y * 64, nb = blockIdx.x * 64;
  const int tid = threadIdx.x;
  #pragma unroll
  for (int i = 0; i < 4; ++i) {
    int u = tid + i * 256;                 // 1024 float4 units
    int r = u >> 4, c4 = u & 15;
    float4 v = *(const float4*)(src + (size_t)(kb + r) * ld + c0 + nb + c4 * 4);
    t[r][c4*4+0] = v.x; t[r][c4*4+1] = v.y; t[r][c4*4+2] = v.z; t[r][c4*4+3] = v.w;
  }
  __syncthreads();
  #pragma unroll
  for (int i = 0; i < 2; ++i) {
    int u = tid + i * 256;                 // 512 units: 64 n-rows x 8 k-groups
    int rn = u >> 3, g = u & 7;
    unsigned short o[8];
    #pragma unroll
    for (int j = 0; j < 8; ++j) o[j] = f2bf(t[g*8+j][rn]);
    *(uint4*)(dst + (size_t)(nb + rn) * Krows + kb + g * 8) = *(uint4*)o;
  }
}

// ---------------- fp32 tiled GEMM (q only): C = A[M,K]*B[K,N], B ld=LDB -----
template<int M, int N, int KD, int LDB>
__global__ __launch_bounds__(256)
void gemm_f32(const float* __restrict__ A, const float* __restrict__ Bm,
              float* __restrict__ C) {
  constexpr int BM = 128, BN = 128, BK = 16;
  __shared__ float As[BK][BM + 4];
  __shared__ float Bs[BK][BN + 4];
  const int tid = threadIdx.x;
  const int tx = tid & 15, ty = tid >> 4;
  const int m0 = blockIdx.y * BM, n0 = blockIdx.x * BN;

  float acc[8][8];
  #pragma unroll
  for (int i = 0; i < 8; ++i)
    #pragma unroll
    for (int j = 0; j < 8; ++j) acc[i][j] = 0.f;

  for (int kt = 0; kt < KD; kt += BK) {
    #pragma unroll
    for (int i = 0; i < 2; ++i) {
      int f = tid + i * 256;
      int row = f >> 2, kq = f & 3;
      float4 a = *(const float4*)(A + (size_t)(m0 + row) * KD + kt + kq * 4);
      As[kq*4+0][row] = a.x; As[kq*4+1][row] = a.y;
      As[kq*4+2][row] = a.z; As[kq*4+3][row] = a.w;
    }
    #pragma unroll
    for (int i = 0; i < 2; ++i) {
      int f = tid + i * 256;
      int kr = f >> 5, nq = f & 31;
      *(float4*)&Bs[kr][nq*4] =
          *(const float4*)(Bm + (size_t)(kt + kr) * LDB + n0 + nq * 4);
    }
    __syncthreads();
    #pragma unroll
    for (int k = 0; k < BK; ++k) {
      float a[8], b[8];
      *(float4*)&a[0] = *(const float4*)&As[k][ty * 8];
      *(float4*)&a[4] = *(const float4*)&As[k][ty * 8 + 4];
      *(float4*)&b[0] = *(const float4*)&Bs[k][tx * 8];
      *(float4*)&b[4] = *(const float4*)&Bs[k][tx * 8 + 4];
      #pragma unroll
      for (int i = 0; i < 8; ++i)
        #pragma unroll
        for (int j = 0; j < 8; ++j) acc[i][j] = fmaf(a[i], b[j], acc[i][j]);
    }
    __syncthreads();
  }
  #pragma unroll
  for (int i = 0; i < 8; ++i) {
    float* cp = C + (size_t)(m0 + ty * 8 + i) * N + n0 + tx * 8;
    *(float4*)cp = make_float4(acc[i][0], acc[i][1], acc[i][2], acc[i][3]);
    *(float4*)(cp + 4) = make_float4(acc[i][4], acc[i][5], acc[i][6], acc[i][7]);
  }
}

// ---------------- bf16 MFMA GEMM: C[M,N] = A[M,K] * Bt[N,K]^T ---------------
// 128x128 tile, BK=64, 4 waves (2x2), each wave 64x64 via 4x4 16x16x32 MFMAs.
template<int N, int KD, bool OBF>
__global__ __launch_bounds__(256)
void gemm_bf16(const unsigned short* __restrict__ A,
               const unsigned short* __restrict__ Bt,
               void* __restrict__ C) {
  __shared__ __align__(16) unsigned short As[128][72];  // [m][k], +8 pad
  __shared__ __align__(16) unsigned short Bs[128][72];  // [n][k], +8 pad
  const int tid = threadIdx.x;
  const int w = tid >> 6, L = tid & 63, Ln = L & 15, Lq = L >> 4;
  const int wm = w & 1, wn = w >> 1;
  const int m0 = blockIdx.y * 128, n0 = blockIdx.x * 128;

  floatx4 acc[4][4];
  #pragma unroll
  for (int mt = 0; mt < 4; ++mt)
    #pragma unroll
    for (int nt = 0; nt < 4; ++nt) acc[mt][nt] = (floatx4)0.f;

  for (int kt = 0; kt < KD; kt += 64) {
    #pragma unroll
    for (int i = 0; i < 4; ++i) {
      int u = tid + i * 256;               // 1024 uint4 units per operand
      int row = u >> 3, g = u & 7;
      *(uint4*)&As[row][g*8] = *(const uint4*)(A + (size_t)(m0 + row) * KD + kt + g * 8);
      *(uint4*)&Bs[row][g*8] = *(const uint4*)(Bt + (size_t)(n0 + row) * KD + kt + g * 8);
    }
    __syncthreads();
    #pragma unroll
    for (int kc = 0; kc < 2; ++kc) {
      short8 af[4], bfr[4];
      #pragma unroll
      for (int mt = 0; mt < 4; ++mt)
        af[mt] = *(const short8*)&As[wm*64 + mt*16 + Ln][kc*32 + Lq*8];
      #pragma unroll
      for (int nt = 0; nt < 4; ++nt)
        bfr[nt] = *(const short8*)&Bs[wn*64 + nt*16 + Ln][kc*32 + Lq*8];
      #pragma unroll
      for (int mt = 0; mt < 4; ++mt)
        #pragma unroll
        for (int nt = 0; nt < 4; ++nt)
          acc[mt][nt] = __builtin_amdgcn_mfma_f32_16x16x32_bf16(af[mt], bfr[nt], acc[mt][nt], 0, 0, 0);
    }
    __syncthreads();
  }
  #pragma unroll
  for (int mt = 0; mt < 4; ++mt)
    #pragma unroll
    for (int nt = 0; nt < 4; ++nt)
      #pragma unroll
      for (int r = 0; r < 4; ++r) {
        size_t row = m0 + wm*64 + mt*16 + Lq*4 + r;
        int col = n0 + wn*64 + nt*16 + Ln;
        if (OBF) ((unsigned short*)C)[row * N + col] = f2bf(acc[mt][nt][r]);
        else     ((float*)C)[row * N + col] = acc[mt][nt][r];
      }
}

// ---------------- causal flash attention, bf16 MFMA -------------------------
// q fp32 [M,Ed]; kv bf16 [M,2048] (k cols 0..1023, v cols 1024..2047); y bf16.
__global__ __launch_bounds__(256)
void flash_mfma(const float* __restrict__ qf, const unsigned short* __restrict__ kv,
                unsigned short* __restrict__ y) {
  __shared__ __align__(16) unsigned short Ks[64 * 64];      // [key][d] swizzled
  __shared__ __align__(16) unsigned short Vt[64 * 64];      // [d][key] swizzled
  __shared__ __align__(16) unsigned short Ps[4][32 * 64];   // per-wave [qrow][key]
  const int q = blockIdx.x;
  const int bh = blockIdx.y;
  const int b = bh >> 4, h = bh & 15;
  const int tid = threadIdx.x;
  const int w = tid >> 6, L = tid & 63;
  const int Ln = L & 15, Lq = L >> 4;
  const size_t base = (size_t)b * Tseq;
  const int q0 = q * 128;
  const int hof = h * 64;

  // Q A-fragments, fp32 global -> bf16 regs
  short8 qfr[2][2];
  #pragma unroll
  for (int mt = 0; mt < 2; ++mt) {
    const float* qp = qf + (base + q0 + w*32 + mt*16 + Ln) * Ed + hof;
    #pragma unroll
    for (int kc = 0; kc < 2; ++kc) {
      float v[8];
      *(float4*)&v[0] = *(const float4*)(qp + kc*32 + Lq*8);
      *(float4*)&v[4] = *(const float4*)(qp + kc*32 + Lq*8 + 4);
      short8 t;
      #pragma unroll
      for (int j = 0; j < 8; ++j) t[j] = (short)f2bf(v[j]);
      qfr[mt][kc] = t;
    }
  }

  float m_i[2][4], l_i[2][4];
  floatx4 O[2][4];
  #pragma unroll
  for (int mt = 0; mt < 2; ++mt)
    #pragma unroll
    for (int r = 0; r < 4; ++r) { m_i[mt][r] = -3.0e38f; l_i[mt][r] = 0.f; }
  #pragma unroll
  for (int mt = 0; mt < 2; ++mt)
    #pragma unroll
    for (int nt = 0; nt < 4; ++nt) O[mt][nt] = (floatx4)0.f;

  const int nkt = 2 * q + 2;
  for (int kt = 0; kt < nkt; ++kt) {
    // ---- stage K (natural, group-swizzled) and V (transposed) ----
    #pragma unroll
    for (int i = 0; i < 2; ++i) {
      int u = tid + i * 256;               // 512 uint4 units per operand
      int c = u >> 3, g = u & 7;
      const unsigned short* kvp = kv + (base + kt*64 + c) * 2048 + hof + g * 8;
      uint4 k4 = *(const uint4*)kvp;
      *(uint4*)&Ks[c*64 + (((g ^ (c & 7)) << 3))] = k4;
      unsigned short vv[8];
      *(uint4*)vv = *(const uint4*)(kvp + 1024);
      #pragma unroll
      for (int j = 0; j < 8; ++j) Vt[swz(g*8 + j, c)] = vv[j];
    }
    __syncthreads();

    // ---- S = Q K^T ----
    short8 kb[4][2];
    #pragma unroll
    for (int nt = 0; nt < 4; ++nt) {
      int krow = nt*16 + Ln;
      #pragma unroll
      for (int kc = 0; kc < 2; ++kc)
        kb[nt][kc] = *(const short8*)&Ks[krow*64 + ((((kc*4 + Lq) ^ (krow & 7)) << 3))];
    }
    floatx4 S[2][4];
    #pragma unroll
    for (int mt = 0; mt < 2; ++mt)
      #pragma unroll
      for (int nt = 0; nt < 4; ++nt) {
        floatx4 a = (floatx4)0.f;
        a = __builtin_amdgcn_mfma_f32_16x16x32_bf16(qfr[mt][0], kb[nt][0], a, 0, 0, 0);
        a = __builtin_amdgcn_mfma_f32_16x16x32_bf16(qfr[mt][1], kb[nt][1], a, 0, 0, 0);
        S[mt][nt] = a;
      }

    #pragma unroll
    for (int mt = 0; mt < 2; ++mt)
      #pragma unroll
      for (int nt = 0; nt < 4; ++nt)
        #pragma unroll
        for (int r = 0; r < 4; ++r) S[mt][nt][r] *= 0.125f;
    if (kt >= 2*q) {
      #pragma unroll
      for (int mt = 0; mt < 2; ++mt) {
        int rowg = q0 + w*32 + mt*16 + Lq*4;
        #pragma unroll
        for (int nt = 0; nt < 4; ++nt) {
          int colg = kt*64 + nt*16 + Ln;
          #pragma unroll
          for (int r = 0; r < 4; ++r)
            if (colg > rowg + r) S[mt][nt][r] = -3.0e38f;
        }
      }
    }

    // ---- online softmax ----
    #pragma unroll
    for (int mt = 0; mt < 2; ++mt) {
      #pragma unroll
      for (int r = 0; r < 4; ++r) {
        float mx = fmaxf(fmaxf(S[mt][0][r], S[mt][1][r]),
                         fmaxf(S[mt][2][r], S[mt][3][r]));
        mx = fmaxf(mx, __shfl_xor(mx, 1));
        mx = fmaxf(mx, __shfl_xor(mx, 2));
        mx = fmaxf(mx, __shfl_xor(mx, 4));
        mx = fmaxf(mx, __shfl_xor(mx, 8));
        float mnew = fmaxf(m_i[mt][r], mx);
        float alpha = __expf(m_i[mt][r] - mnew);
        m_i[mt][r] = mnew;
        float rs = 0.f;
        #pragma unroll
        for (int nt = 0; nt < 4; ++nt) {
          float p = __expf(S[mt][nt][r] - mnew);
          S[mt][nt][r] = p;
          rs += p;
        }
        rs += __shfl_xor(rs, 1);
        rs += __shfl_xor(rs, 2);
        rs += __shfl_xor(rs, 4);
        rs += __shfl_xor(rs, 8);
        l_i[mt][r] = l_i[mt][r] * alpha + rs;
        #pragma unroll
        for (int nt = 0; nt < 4; ++nt) O[mt][nt][r] *= alpha;
        int prow = mt*16 + Lq*4 + r;
        #pragma unroll
        for (int nt = 0; nt < 4; ++nt)
          Ps[w][swz(prow, nt*16 + Ln)] = f2bf(S[mt][nt][r]);
      }
    }

    // ---- O += P V ----
    short8 vb[4][2], pf[2][2];
    #pragma unroll
    for (int nt = 0; nt < 4; ++nt) {
      int vrow = nt*16 + Ln;
      #pragma unroll
      for (int kc = 0; kc < 2; ++kc)
        vb[nt][kc] = *(const short8*)&Vt[vrow*64 + ((((kc*4 + Lq) ^ (vrow & 7)) << 3))];
    }
    #pragma unroll
    for (int mt = 0; mt < 2; ++mt) {
      int prow = mt*16 + Ln;
      #pragma unroll
      for (int kc = 0; kc < 2; ++kc)
        pf[mt][kc] = *(const short8*)&Ps[w][prow*64 + ((((kc*4 + Lq) ^ (prow & 7)) << 3))];
    }
    #pragma unroll
    for (int mt = 0; mt < 2; ++mt)
      #pragma unroll
      for (int nt = 0; nt < 4; ++nt) {
        O[mt][nt] = __builtin_amdgcn_mfma_f32_16x16x32_bf16(pf[mt][0], vb[nt][0], O[mt][nt], 0, 0, 0);
        O[mt][nt] = __builtin_amdgcn_mfma_f32_16x16x32_bf16(pf[mt][1], vb[nt][1], O[mt][nt], 0, 0, 0);
      }
    __syncthreads();
  }

  // epilogue -> y bf16
  #pragma unroll
  for (int mt = 0; mt < 2; ++mt) {
    #pragma unroll
    for (int r = 0; r < 4; ++r) {
      float inv = 1.f / l_i[mt][r];
      size_t rb = (base + q0 + w*32 + mt*16 + Lq*4 + r) * Ed + hof;
      #pragma unroll
      for (int nt = 0; nt < 4; ++nt)
        y[rb + nt*16 + Ln] = f2bf(O[mt][nt][r] * inv);
    }
  }
}

// ---------------- mem attention (K=3, scale 4096) + gated fusion ------------
// q fp32; y bf16 updated in place with combined.
__global__ __launch_bounds__(256)
void mem_gate(const float* __restrict__ qf, const float* __restrict__ mem_k,
              const float* __restrict__ mem_v, const float* __restrict__ gate,
              unsigned short* __restrict__ y) {
  const int tid = threadIdx.x;
  const int lane = tid & 63;
  const int g = (blockIdx.x << 2) | (tid >> 6);
  const int h = g & 15;
  const int bt = g >> 4;
  const float q = qf[(size_t)bt * Ed + h*64 + lane];
  const size_t mb = ((size_t)bt * 3) * Ed + h*64 + lane;

  float s[3];
  #pragma unroll
  for (int k = 0; k < 3; ++k) {
    float p = q * mem_k[mb + (size_t)k * Ed];
    p += __shfl_xor(p, 1);  p += __shfl_xor(p, 2);  p += __shfl_xor(p, 4);
    p += __shfl_xor(p, 8);  p += __shfl_xor(p, 16); p += __shfl_xor(p, 32);
    s[k] = p * 4096.0f;
  }
  float mx = fmaxf(s[0], fmaxf(s[1], s[2]));
  float w0 = __expf(s[0] - mx), w1 = __expf(s[1] - mx), w2 = __expf(s[2] - mx);
  float inv = 1.f / (w0 + w1 + w2);
  float ov = (w0 * mem_v[mb] + w1 * mem_v[mb + Ed] + w2 * mem_v[mb + 2*Ed]) * inv;
  float gb = gate[h];
  unsigned short* yp = y + (size_t)bt * Ed + h*64 + lane;
  float yv = bf2f(*yp);
  *yp = f2bf(ov * gb + yv * (1.f - gb));
}

extern "C" void kernel_launch(void* const* d_in, const int* in_sizes, int n_in,
                              void* d_out, int out_size, void* d_ws, size_t ws_size,
                              hipStream_t stream) {
  const float* x      = (const float*)d_in[0];
  const float* mem_k  = (const float*)d_in[1];
  const float* mem_v  = (const float*)d_in[2];
  const float* W_attn = (const float*)d_in[3];
  const float* W_proj = (const float*)d_in[4];
  const float* gate   = (const float*)d_in[5];
  float* out = (float*)d_out;

  // workspace layout (~107 MB)
  float* qf32          = (float*)d_ws;                       // [M,1024] f32
  unsigned short* kvb  = (unsigned short*)(qf32 + (size_t)MROWS*Ed);  // [M,2048] bf16
  unsigned short* ybf  = kvb + (size_t)MROWS*2048;           // [M,1024] bf16
  unsigned short* xb   = ybf + (size_t)MROWS*Ed;             // [M,1024] bf16
  unsigned short* wkv  = xb  + (size_t)MROWS*Ed;             // [2048,1024] bf16
  unsigned short* wp   = wkv + (size_t)2048*Ed;              // [1024,1024] bf16

  // 0) casts / transposes
  cast_bf16_k<<<(MROWS*Ed/4 + 255)/256, 256, 0, stream>>>(x, xb, MROWS*Ed/4);
  transpose_cast<<<dim3(2048/64, Ed/64), 256, 0, stream>>>(W_attn, E3, Ed, wkv, Ed);
  transpose_cast<<<dim3(Ed/64, Ed/64), 256, 0, stream>>>(W_proj, Ed, 0, wp, Ed);
  // 1) q = x @ W_attn[:, :1024]  (fp32 — mem-attn needs fp32 q)
  gemm_f32<MROWS, Ed, Ed, E3>
      <<<dim3(Ed/128, MROWS/128), 256, 0, stream>>>(x, W_attn, qf32);
  // 2) kv = xb @ wkv^T  (bf16 MFMA, bf16 out)
  gemm_bf16<2048, Ed, true>
      <<<dim3(2048/128, MROWS/128), 256, 0, stream>>>(xb, wkv, kvb);
  // 3) y = causal SDPA
  flash_mfma<<<dim3(Tseq/128, Bsz*Hh), 256, 0, stream>>>(qf32, kvb, ybf);
  // 4) y = gate*memattn + (1-gate)*y  (in place, bf16)
  mem_gate<<<(MROWS*Hh)/4, 256, 0, stream>>>(qf32, mem_k, mem_v, gate, ybf);
  // 5) out = y @ wp^T  (bf16 MFMA, fp32 out)
  gemm_bf16<Ed, Ed, false>
      <<<dim3(Ed/128, MROWS/128), 256, 0, stream>>>(ybf, wp, out);
}